// Round 13
// baseline (96.148 us; speedup 1.0000x reference)
//
#include <hip/hip_runtime.h>

#define NLAT 192
#define NPTS 40320
#define MMAX 96
#define LMAX 96
#define NV   100
#define MAXN 400
#define NB   400   // total B rows = 4 * NV

typedef __attribute__((ext_vector_type(8))) _Float16 half8v;  // 8 f16 (4 VGPRs)
typedef __attribute__((ext_vector_type(4))) float f32x4;

static __device__ __forceinline__ float bits2f(unsigned int b) {
    union { unsigned int i; float f; } v; v.i = b; return v.f;
}
static __device__ __forceinline__ unsigned int f2bf(float f) {
    union { float f; unsigned int i; } v; v.f = f;
    return (v.i + 0x7FFFu + ((v.i >> 16) & 1u)) >> 16;
}
static __device__ __forceinline__ unsigned short f2h(float f) {
    union { _Float16 h; unsigned short s; } u; u.h = (_Float16)f; return u.s;
}
static __device__ __forceinline__ float h2f(unsigned short s) {
    union { _Float16 h; unsigned short s; } u; u.s = s; return (float)u.h;
}
// split f32 pair -> hi f16 pair (RNE) + lo f16 pair (residual, RNE)
static __device__ __forceinline__ void split2(float a, float b,
                                              unsigned int& hw, unsigned int& lw) {
    unsigned short h0 = f2h(a), h1 = f2h(b);
    unsigned short l0 = f2h(a - h2f(h0)), l1 = f2h(b - h2f(h1));
    hw = (unsigned int)h0 | ((unsigned int)h1 << 16);
    lw = (unsigned int)l0 | ((unsigned int)l1 << 16);
}

// S(n) = sum_{t<n} floor(t/8)
static __device__ __forceinline__ int Ssum(int n) {
    int q = n >> 3, r = n & 7; return 4 * q * (q - 1) + q * r;
}
// padded-32 k-units before ring j in At (ragged layout); total = 43008
static __device__ __forceinline__ int atoffk(int j) {
    if (j < 96) return 32 * (Ssum(j + 12) - 4);
    return 32 * (672 + 676 - Ssum(204 - j));
}
static __device__ __forceinline__ int kpad_of(int j) {
    return 32 * ((j < 96 ? (j + 12) : (203 - j)) >> 3);
}

// ---------------- K0a: split leg fp32 -> f16 hi/lo, relayout [l][m][j] -> [m][l][j]
__global__ __launch_bounds__(256) void leg_conv_kernel(
    const float* __restrict__ leg,    // [96 l][96 m][192 j]
    unsigned short* __restrict__ legh,
    unsigned short* __restrict__ legl)
{
    int idx = blockIdx.x * 256 + threadIdx.x;
    if (idx >= 96 * 96 * 192) return;
    int j = idx % 192;
    int lm = idx / 192;
    int m = lm % 96, l = lm / 96;
    float v = leg[idx];
    unsigned short h = f2h(v);
    unsigned short lo = f2h(v - h2f(h));
    size_t o = ((size_t)m * 96 + l) * 192 + j;
    legh[o] = h;
    legl[o] = lo;
}

// ---------------- K0b: transpose dft words into At (f16), k-step-blocked:
// At[j]: per k-step t, contiguous [192 rows][32 k] f16 (12288 B)
__global__ __launch_bounds__(256) void dft_transpose_kernel(
    const unsigned int* __restrict__ dftw,   // [192][400][96] (bf16 re | im<<16)
    unsigned short* __restrict__ At)
{
    const int j = blockIdx.x;
    const int kpad = kpad_of(j);
    const int t = blockIdx.y;
    const int k0 = t * 32;
    if (k0 >= kpad) return;
    const int n = j < 96 ? 20 + 4 * j : 400 - 4 * (j - 96);
    unsigned short* abase = At + (size_t)atoffk(j) * 192 + (size_t)t * 6144;
    const int tid = threadIdx.x;
#pragma unroll
    for (int s = 0; s < 3; ++s) {
        int slot = s * 256 + tid;          // 768 = 192 rows x 4 chunks
        int row = slot % 192;
        int ch  = slot / 192;
        int m = row < 96 ? row : row - 96;
        bool isIm = row >= 96;
        const unsigned int* dp = dftw + ((size_t)j * MAXN + k0 + ch * 8) * 96 + m;
        unsigned short o[8];
#pragma unroll
        for (int i = 0; i < 8; ++i) {
            int k = k0 + ch * 8 + i;
            unsigned int v = (k < n) ? dp[(size_t)i * 96] : 0u;
            float f = isIm ? bits2f(v & 0xFFFF0000u) : bits2f(v << 16);
            o[i] = f2h(f);
        }
        uint4 pk;
        pk.x = (unsigned int)o[0] | ((unsigned int)o[1] << 16);
        pk.y = (unsigned int)o[2] | ((unsigned int)o[3] << 16);
        pk.z = (unsigned int)o[4] | ((unsigned int)o[5] << 16);
        pk.w = (unsigned int)o[6] | ((unsigned int)o[7] << 16);
        *(uint4*)(abase + (size_t)row * 32 + ch * 8) = pk;
    }
}

// ---------------- K1 (MFMA f16): ring DFT GEMM — NO LDS, NO BARRIERS.
// All fragments per-lane direct from global: A contiguous 16B (L2-resident,
// same-XCD); X per-col f32 loads (64B coalesced across lr), hi/lo f16 split
// in-register. 4 waves independent; loads pipeline under VALU+MFMA freely.
__global__ __launch_bounds__(256) void dft_mfma_kernel(
    const float* __restrict__ data,          // [4][NPTS][NV] fp32
    const unsigned short* __restrict__ At,   // ragged [j][t][192][32] f16
    unsigned short* __restrict__ fh,         // [NLAT][192][cn] f16
    int c0, int cn)
{
    const int id  = blockIdx.x;
    const int j   = id % 192;                // same-ring blocks -> same XCD
    const int bt  = id / 192;
    const int tid = threadIdx.x;
    const int w   = tid >> 6;
    const int l   = tid & 63;
    const int lr  = l & 15;
    const int kg  = l >> 4;

    int n, start;
    if (j < 96) { n = 20 + 4 * j; start = 2 * j * j + 18 * j; }
    else { int jj = j - 96; n = 400 - 4 * jj; start = 20160 + 402 * jj - 2 * jj * jj; }
    const int nsteps = kpad_of(j) >> 5;
    const half8v* avbase = (const half8v*)(At + (size_t)atoffk(j) * 192);

    const int Bb = c0 + bt * 50;
    const int bb = Bb / NV;
    const int vb = Bb % NV;
    const float* dbase = data + (size_t)bb * NPTS * NV + vb;

    f32x4 acc[3][4];
#pragma unroll
    for (int i = 0; i < 3; ++i)
#pragma unroll
        for (int nt = 0; nt < 4; ++nt) acc[i][nt] = (f32x4){0.f, 0.f, 0.f, 0.f};

    float xf[4][8];
    // ---- prologue: X(0) loads
#pragma unroll
    for (int nt = 0; nt < 4; ++nt) {
        int c = nt * 16 + lr;
        const float* sp = dbase + (size_t)(start + kg * 8) * NV + c;
#pragma unroll
        for (int i = 0; i < 8; ++i) {
            int k = kg * 8 + i;
            xf[nt][i] = (c < 50 && k < n) ? sp[(size_t)i * NV] : 0.f;
        }
    }

    for (int t = 0; t < nsteps; ++t) {
        // issue A(t) loads (L2 latency hides under the converts below)
        const half8v* av = avbase + (size_t)t * 768;
        half8v a0 = av[((3 * w + 0) * 16 + lr) * 4 + kg];
        half8v a1 = av[((3 * w + 1) * 16 + lr) * 4 + kg];
        half8v a2 = av[((3 * w + 2) * 16 + lr) * 4 + kg];

        // convert X(t) -> hi/lo f16 fragments (VALU)
        unsigned int BH[4][4], BL[4][4];
#pragma unroll
        for (int nt = 0; nt < 4; ++nt)
#pragma unroll
            for (int q = 0; q < 4; ++q)
                split2(xf[nt][2 * q], xf[nt][2 * q + 1], BH[nt][q], BL[nt][q]);

        // issue X(t+1) loads (in flight across MFMA + next converts)
        if (t + 1 < nsteps) {
            int kb = (t + 1) * 32 + kg * 8;
#pragma unroll
            for (int nt = 0; nt < 4; ++nt) {
                int c = nt * 16 + lr;
                const float* sp = dbase + (size_t)(start + kb) * NV + c;
#pragma unroll
                for (int i = 0; i < 8; ++i) {
                    int k = kb + i;
                    xf[nt][i] = (c < 50 && k < n) ? sp[(size_t)i * NV] : 0.f;
                }
            }
        }

        // MFMA(t)
#pragma unroll
        for (int nt = 0; nt < 4; ++nt) {
            union { uint4 u; half8v h; } ub, ul2;
            ub.u = (uint4){BH[nt][0], BH[nt][1], BH[nt][2], BH[nt][3]};
            ul2.u = (uint4){BL[nt][0], BL[nt][1], BL[nt][2], BL[nt][3]};
            half8v bh = ub.h, bl = ul2.h;
            acc[0][nt] = __builtin_amdgcn_mfma_f32_16x16x32_f16(a0, bh, acc[0][nt], 0, 0, 0);
            acc[1][nt] = __builtin_amdgcn_mfma_f32_16x16x32_f16(a1, bh, acc[1][nt], 0, 0, 0);
            acc[2][nt] = __builtin_amdgcn_mfma_f32_16x16x32_f16(a2, bh, acc[2][nt], 0, 0, 0);
            acc[0][nt] = __builtin_amdgcn_mfma_f32_16x16x32_f16(a0, bl, acc[0][nt], 0, 0, 0);
            acc[1][nt] = __builtin_amdgcn_mfma_f32_16x16x32_f16(a1, bl, acc[1][nt], 0, 0, 0);
            acc[2][nt] = __builtin_amdgcn_mfma_f32_16x16x32_f16(a2, bl, acc[2][nt], 0, 0, 0);
        }
    }

    // ---- epilogue: C/D col=lane&15 (B), row=(lane>>4)*4+reg (mm); emit f16
#pragma unroll
    for (int i = 0; i < 3; ++i)
#pragma unroll
        for (int nt = 0; nt < 4; ++nt) {
            int c = nt * 16 + lr;
            if (c < 50) {
                int Brel = bt * 50 + c;
                int mm0 = (3 * w + i) * 16 + kg * 4;
                unsigned short* oh = fh + ((size_t)j * 192 + mm0) * cn + Brel;
#pragma unroll
                for (int r = 0; r < 4; ++r)
                    oh[(size_t)r * cn] = f2h(acc[i][nt][r]);
            }
        }
}

// ---------------- K2 (MFMA f16): Legendre contraction — NO LDS, NO BARRIERS.
// C[l, B] = sum_j leg[l,m,j] * fh[j, m+96pl, B]; leg hi/lo direct 16B loads,
// F per-lane ushort loads (L2/L3-resident fh).
__global__ __launch_bounds__(256) void leg_mfma_kernel(
    const unsigned short* __restrict__ legh,  // [96 m][96 l][192 j] f16
    const unsigned short* __restrict__ legl,
    const unsigned short* __restrict__ fh,    // [192 j][192 mm][cn] f16
    unsigned int* __restrict__ out,           // [4][LMAX][MMAX][NV] packed bf16
    int c0, int cn)
{
    const int m   = blockIdx.x;
    const int bt  = blockIdx.y;
    const int tid = threadIdx.x;
    const int w   = tid >> 6;
    const int l   = tid & 63;
    const int lr  = l & 15;
    const int kg  = l >> 4;

    const int c  = w * 16 + lr;
    const bool cok = c < 50;
    const int col = bt * 50 + (cok ? c : 0);

    f32x4 acc[6][2];
#pragma unroll
    for (int lt = 0; lt < 6; ++lt)
#pragma unroll
        for (int pl = 0; pl < 2; ++pl) acc[lt][pl] = (f32x4){0.f, 0.f, 0.f, 0.f};

    for (int j0 = 0; j0 < NLAT; j0 += 32) {
        // A: leg hi/lo fragments, contiguous 16B per (lt,hl)
        half8v ah[6], al[6];
#pragma unroll
        for (int lt = 0; lt < 6; ++lt) {
            size_t o = ((size_t)m * 96 + lt * 16 + lr) * 192 + j0 + kg * 8;
            ah[lt] = *(const half8v*)&legh[o];
            al[lt] = *(const half8v*)&legl[o];
        }
        // F: per-plane 8 ushort loads (k = j0+kg*8+i), packed to fragments
        half8v fF[2];
#pragma unroll
        for (int pl = 0; pl < 2; ++pl) {
            union { half8v h; unsigned short s[8]; } uf;
#pragma unroll
            for (int i = 0; i < 8; ++i)
                uf.s[i] = fh[((size_t)(j0 + kg * 8 + i) * 192 + m + 96 * pl) * cn + col];
            fF[pl] = uf.h;
        }
#pragma unroll
        for (int lt = 0; lt < 6; ++lt)
#pragma unroll
            for (int pl = 0; pl < 2; ++pl) {
                acc[lt][pl] = __builtin_amdgcn_mfma_f32_16x16x32_f16(ah[lt], fF[pl], acc[lt][pl], 0, 0, 0);
                acc[lt][pl] = __builtin_amdgcn_mfma_f32_16x16x32_f16(al[lt], fF[pl], acc[lt][pl], 0, 0, 0);
            }
    }

    if (cok) {
        int B = c0 + bt * 50 + c;
        int bb = B / NV, vv = B % NV;
#pragma unroll
        for (int lt = 0; lt < 6; ++lt) {
#pragma unroll
            for (int r = 0; r < 4; ++r) {
                int ll = lt * 16 + kg * 4 + r;
                out[(((size_t)bb * LMAX + ll) * MMAX + m) * NV + vv] =
                    f2bf(acc[lt][0][r]) | (f2bf(acc[lt][1][r]) << 16);
            }
        }
    }
}

extern "C" void kernel_launch(void* const* d_in, const int* in_sizes, int n_in,
                              void* d_out, int out_size, void* d_ws, size_t ws_size,
                              hipStream_t stream) {
    if (n_in != 3) return;

    const float* data = (const float*)d_in[0];
    const unsigned int* dftw = (const unsigned int*)d_in[1];
    const float* leg  = (const float*)d_in[2];
    unsigned int* out = (unsigned int*)d_out;

    // ws: [legh][legl][At][fh]
    const size_t LEGN = (size_t)96 * 96 * 192;
    const size_t LEGB = 2 * LEGN * sizeof(unsigned short);   // 7.08 MB
    const size_t ATN  = (size_t)43008 * 192;                 // shorts
    const size_t ATB  = ATN * sizeof(unsigned short);        // 16.5 MB
    const size_t rowb = (size_t)192 * 192 * sizeof(unsigned short); // 73728 B / B-row
    if (ws_size < LEGB + ATB + 50 * rowb) return;

    unsigned short* legh = (unsigned short*)d_ws;
    unsigned short* legl = legh + LEGN;
    unsigned short* At   = legl + LEGN;

    size_t maxrows = (ws_size - LEGB - ATB) / rowb;
    int chunk = (int)((maxrows / 50) * 50);
    if (chunk > NB) chunk = NB;

    leg_conv_kernel<<<dim3((96 * 96 * 192 + 255) / 256), dim3(256), 0, stream>>>(
        leg, legh, legl);
    dft_transpose_kernel<<<dim3(192, 13), dim3(256), 0, stream>>>(dftw, At);

    for (int c0 = 0; c0 < NB; c0 += chunk) {
        int cn = NB - c0 < chunk ? NB - c0 : chunk;
        unsigned short* fh = At + ATN;

        int nbt = cn / 50;
        dim3 g1(192 * nbt);
        dft_mfma_kernel<<<g1, dim3(256), 0, stream>>>(data, At, fh, c0, cn);
        dim3 g2(96, nbt);
        leg_mfma_kernel<<<g2, dim3(256), 0, stream>>>(legh, legl, fh, out, c0, cn);
    }
}

// Round 14
// 93.986 us; speedup vs baseline: 1.0230x; 1.0230x over previous
//
#include <hip/hip_runtime.h>

#define NLAT 192
#define NPTS 40320
#define MMAX 96
#define LMAX 96
#define NV   100
#define MAXN 400
#define NB   400   // total B rows = 4 * NV

typedef __attribute__((ext_vector_type(8))) _Float16 half8v;  // 8 f16 (4 VGPRs)
typedef __attribute__((ext_vector_type(4))) float f32x4;

static __device__ __forceinline__ float bits2f(unsigned int b) {
    union { unsigned int i; float f; } v; v.i = b; return v.f;
}
static __device__ __forceinline__ unsigned int f2bf(float f) {
    union { float f; unsigned int i; } v; v.f = f;
    return (v.i + 0x7FFFu + ((v.i >> 16) & 1u)) >> 16;
}
static __device__ __forceinline__ unsigned short f2h(float f) {
    union { _Float16 h; unsigned short s; } u; u.h = (_Float16)f; return u.s;
}
static __device__ __forceinline__ float h2f(unsigned short s) {
    union { _Float16 h; unsigned short s; } u; u.s = s; return (float)u.h;
}
// split f32 pair -> hi f16 pair + lo f16 pair (residual), packed words
static __device__ __forceinline__ void split2(float a, float b,
                                              unsigned int& hw, unsigned int& lw) {
    unsigned short h0 = f2h(a), h1 = f2h(b);
    unsigned short l0 = f2h(a - h2f(h0)), l1 = f2h(b - h2f(h1));
    hw = (unsigned int)h0 | ((unsigned int)h1 << 16);
    lw = (unsigned int)l0 | ((unsigned int)l1 << 16);
}

// S(n) = sum_{t<n} floor(t/8)
static __device__ __forceinline__ int Ssum(int n) {
    int q = n >> 3, r = n & 7; return 4 * q * (q - 1) + q * r;
}
// padded-32 k-units before ring j in At (ragged layout); total = 43008
static __device__ __forceinline__ int atoffk(int j) {
    if (j < 96) return 32 * (Ssum(j + 12) - 4);
    return 32 * (672 + 676 - Ssum(204 - j));
}
static __device__ __forceinline__ int kpad_of(int j) {
    return 32 * ((j < 96 ? (j + 12) : (203 - j)) >> 3);
}

// ---------------- K0a: split leg fp32 -> f16 hi/lo, relayout [l][m][j] -> [m][l][j]
__global__ __launch_bounds__(256) void leg_conv_kernel(
    const float* __restrict__ leg,    // [96 l][96 m][192 j]
    unsigned short* __restrict__ legh,
    unsigned short* __restrict__ legl)
{
    int idx = blockIdx.x * 256 + threadIdx.x;
    if (idx >= 96 * 96 * 192) return;
    int j = idx % 192;
    int lm = idx / 192;
    int m = lm % 96, l = lm / 96;
    float v = leg[idx];
    unsigned short h = f2h(v);
    unsigned short lo = f2h(v - h2f(h));
    size_t o = ((size_t)m * 96 + l) * 192 + j;
    legh[o] = h;
    legl[o] = lo;
}

// ---------------- K0b: transpose dft words into At (f16), k-step-blocked:
// At[j]: per k-step t, contiguous [192 rows][32 k] f16 (12288 B)
__global__ __launch_bounds__(256) void dft_transpose_kernel(
    const unsigned int* __restrict__ dftw,   // [192][400][96] (bf16 re | im<<16)
    unsigned short* __restrict__ At)
{
    const int j = blockIdx.x;
    const int kpad = kpad_of(j);
    const int t = blockIdx.y;
    const int k0 = t * 32;
    if (k0 >= kpad) return;
    const int n = j < 96 ? 20 + 4 * j : 400 - 4 * (j - 96);
    unsigned short* abase = At + (size_t)atoffk(j) * 192 + (size_t)t * 6144;
    const int tid = threadIdx.x;
#pragma unroll
    for (int s = 0; s < 3; ++s) {
        int slot = s * 256 + tid;          // 768 = 192 rows x 4 chunks
        int row = slot % 192;
        int ch  = slot / 192;
        int m = row < 96 ? row : row - 96;
        bool isIm = row >= 96;
        const unsigned int* dp = dftw + ((size_t)j * MAXN + k0 + ch * 8) * 96 + m;
        unsigned short o[8];
#pragma unroll
        for (int i = 0; i < 8; ++i) {
            int k = k0 + ch * 8 + i;
            unsigned int v = (k < n) ? dp[(size_t)i * 96] : 0u;
            float f = isIm ? bits2f(v & 0xFFFF0000u) : bits2f(v << 16);
            o[i] = f2h(f);
        }
        uint4 pk;
        pk.x = (unsigned int)o[0] | ((unsigned int)o[1] << 16);
        pk.y = (unsigned int)o[2] | ((unsigned int)o[3] << 16);
        pk.z = (unsigned int)o[4] | ((unsigned int)o[5] << 16);
        pk.w = (unsigned int)o[6] | ((unsigned int)o[7] << 16);
        *(uint4*)(abase + (size_t)row * 32 + ch * 8) = pk;
    }
}

// ---------------- K1 (MFMA f16): ring DFT GEMM — no LDS/barriers, rebalanced.
// Block = ring-pair (p, 96+p): 14 k-steps constant. Wave w owns B-cols
// w*16..w*16+15 and ALL 12 m-tiles. A + X register double-buffered.
static __device__ __forceinline__ void k1_step(
    const half8v (&acur)[12], half8v (&anxt)[12], float (&xf)[8],
    f32x4 (&acc)[12], int t, int nsteps, int n, int start, int kg,
    int lr, bool cok, int cc, const float* __restrict__ dbase,
    const half8v* __restrict__ avb)
{
    // convert X(t) -> hi/lo fragments
    unsigned int BH[4], BL[4];
#pragma unroll
    for (int q = 0; q < 4; ++q)
        split2(xf[2 * q], xf[2 * q + 1], BH[q], BL[q]);

    if (t + 1 < nsteps) {
        // prefetch X(t+1)
        int kb = (t + 1) * 32 + kg * 8;
#pragma unroll
        for (int i = 0; i < 8; ++i) {
            int k = kb + i;
            xf[i] = (cok && k < n) ? dbase[(size_t)(start + k) * NV + cc] : 0.f;
        }
        // prefetch A(t+1)
        const half8v* avn = avb + (size_t)(t + 1) * 768;
#pragma unroll
        for (int mt = 0; mt < 12; ++mt)
            anxt[mt] = avn[(mt * 16 + lr) * 4 + kg];
    }

    union { uint4 u; half8v h; } ubh, ubl;
    ubh.u = (uint4){BH[0], BH[1], BH[2], BH[3]};
    ubl.u = (uint4){BL[0], BL[1], BL[2], BL[3]};
#pragma unroll
    for (int mt = 0; mt < 12; ++mt) {
        acc[mt] = __builtin_amdgcn_mfma_f32_16x16x32_f16(acur[mt], ubh.h, acc[mt], 0, 0, 0);
        acc[mt] = __builtin_amdgcn_mfma_f32_16x16x32_f16(acur[mt], ubl.h, acc[mt], 0, 0, 0);
    }
}

__global__ __launch_bounds__(256) void dft_mfma_kernel(
    const float* __restrict__ data,          // [4][NPTS][NV] fp32
    const unsigned short* __restrict__ At,   // ragged [j][t][192][32] f16
    unsigned short* __restrict__ fh,         // [NLAT][192][cn] f16
    int c0, int cn)
{
    const int id  = blockIdx.x;
    const int p   = id % 96;                 // ring pair (same-p -> same XCD)
    const int bt  = id / 96;
    const int tid = threadIdx.x;
    const int w   = tid >> 6;
    const int l   = tid & 63;
    const int lr  = l & 15;
    const int kg  = l >> 4;

    const int Bb = c0 + bt * 50;
    const int bb = Bb / NV;
    const int vb = Bb % NV;
    const float* dbase = data + (size_t)bb * NPTS * NV + vb;
    const int cc = w * 16 + lr;              // this wave's B column
    const bool cok = cc < 50;

    for (int rr = 0; rr < 2; ++rr) {
        int j, n, start;
        if (rr == 0) { j = p;      n = 20 + 4 * p;  start = 2 * p * p + 18 * p; }
        else         { j = 96 + p; n = 400 - 4 * p; start = 20160 + 402 * p - 2 * p * p; }
        const int nsteps = kpad_of(j) >> 5;
        const half8v* avb = (const half8v*)(At + (size_t)atoffk(j) * 192);

        f32x4 acc[12];
#pragma unroll
        for (int mt = 0; mt < 12; ++mt) acc[mt] = (f32x4){0.f, 0.f, 0.f, 0.f};

        half8v aA[12], aB[12];
        float xf[8];
        // prologue: A(0), X(0)
#pragma unroll
        for (int mt = 0; mt < 12; ++mt)
            aA[mt] = avb[(mt * 16 + lr) * 4 + kg];
#pragma unroll
        for (int i = 0; i < 8; ++i) {
            int k = kg * 8 + i;
            xf[i] = (cok && k < n) ? dbase[(size_t)(start + k) * NV + cc] : 0.f;
        }

        int t = 0;
        while (true) {
            k1_step(aA, aB, xf, acc, t, nsteps, n, start, kg, lr, cok, cc, dbase, avb);
            if (++t >= nsteps) break;
            k1_step(aB, aA, xf, acc, t, nsteps, n, start, kg, lr, cok, cc, dbase, avb);
            if (++t >= nsteps) break;
        }

        // epilogue: C/D col=lane&15 (B), row=(lane>>4)*4+reg (mm); emit f16
        if (cok) {
            int Brel = bt * 50 + cc;
#pragma unroll
            for (int mt = 0; mt < 12; ++mt) {
#pragma unroll
                for (int r = 0; r < 4; ++r)
                    fh[((size_t)j * 192 + mt * 16 + kg * 4 + r) * cn + Brel] =
                        f2h(acc[mt][r]);
            }
        }
    }
}

// ---------------- K2 (MFMA f16): Legendre contraction — no LDS/barriers,
// F register double-buffered (the scattered-load latency tail).
static __device__ __forceinline__ void k2_step(
    unsigned short (&fcur)[2][8], unsigned short (&fnxt)[2][8],
    f32x4 (&acc)[6][2], int s, int m, int lr, int kg, int col, int cn,
    const unsigned short* __restrict__ legh,
    const unsigned short* __restrict__ legl,
    const unsigned short* __restrict__ fh)
{
    const int j0 = s * 32;
    // A(s): leg hi/lo fragments, contiguous 16B each (L2/L3)
    half8v ah[6], al[6];
#pragma unroll
    for (int lt = 0; lt < 6; ++lt) {
        size_t o = ((size_t)m * 96 + lt * 16 + lr) * 192 + j0 + kg * 8;
        ah[lt] = *(const half8v*)&legh[o];
        al[lt] = *(const half8v*)&legl[o];
    }
    // prefetch F(s+1)
    if (s + 1 < 6) {
        const int jn = (s + 1) * 32 + kg * 8;
#pragma unroll
        for (int pl = 0; pl < 2; ++pl)
#pragma unroll
            for (int i = 0; i < 8; ++i)
                fnxt[pl][i] = fh[((size_t)(jn + i) * 192 + m + 96 * pl) * cn + col];
    }
    // fragments from fcur
    half8v fF[2];
#pragma unroll
    for (int pl = 0; pl < 2; ++pl) {
        union { half8v h; unsigned short s16[8]; } uf;
#pragma unroll
        for (int i = 0; i < 8; ++i) uf.s16[i] = fcur[pl][i];
        fF[pl] = uf.h;
    }
#pragma unroll
    for (int lt = 0; lt < 6; ++lt)
#pragma unroll
        for (int pl = 0; pl < 2; ++pl) {
            acc[lt][pl] = __builtin_amdgcn_mfma_f32_16x16x32_f16(ah[lt], fF[pl], acc[lt][pl], 0, 0, 0);
            acc[lt][pl] = __builtin_amdgcn_mfma_f32_16x16x32_f16(al[lt], fF[pl], acc[lt][pl], 0, 0, 0);
        }
}

__global__ __launch_bounds__(256) void leg_mfma_kernel(
    const unsigned short* __restrict__ legh,  // [96 m][96 l][192 j] f16
    const unsigned short* __restrict__ legl,
    const unsigned short* __restrict__ fh,    // [192 j][192 mm][cn] f16
    unsigned int* __restrict__ out,           // [4][LMAX][MMAX][NV] packed bf16
    int c0, int cn)
{
    const int m   = blockIdx.x;
    const int bt  = blockIdx.y;
    const int tid = threadIdx.x;
    const int w   = tid >> 6;
    const int l   = tid & 63;
    const int lr  = l & 15;
    const int kg  = l >> 4;

    const int c  = w * 16 + lr;
    const bool cok = c < 50;
    const int col = bt * 50 + (cok ? c : 0);

    f32x4 acc[6][2];
#pragma unroll
    for (int lt = 0; lt < 6; ++lt)
#pragma unroll
        for (int pl = 0; pl < 2; ++pl) acc[lt][pl] = (f32x4){0.f, 0.f, 0.f, 0.f};

    unsigned short fA[2][8], fB[2][8];
    // prologue: F(0)
#pragma unroll
    for (int pl = 0; pl < 2; ++pl)
#pragma unroll
        for (int i = 0; i < 8; ++i)
            fA[pl][i] = fh[((size_t)(kg * 8 + i) * 192 + m + 96 * pl) * cn + col];

#pragma unroll
    for (int ss = 0; ss < 3; ++ss) {
        k2_step(fA, fB, acc, 2 * ss,     m, lr, kg, col, cn, legh, legl, fh);
        k2_step(fB, fA, acc, 2 * ss + 1, m, lr, kg, col, cn, legh, legl, fh);
    }

    if (cok) {
        int B = c0 + bt * 50 + c;
        int bb = B / NV, vv = B % NV;
#pragma unroll
        for (int lt = 0; lt < 6; ++lt) {
#pragma unroll
            for (int r = 0; r < 4; ++r) {
                int ll = lt * 16 + kg * 4 + r;
                out[(((size_t)bb * LMAX + ll) * MMAX + m) * NV + vv] =
                    f2bf(acc[lt][0][r]) | (f2bf(acc[lt][1][r]) << 16);
            }
        }
    }
}

extern "C" void kernel_launch(void* const* d_in, const int* in_sizes, int n_in,
                              void* d_out, int out_size, void* d_ws, size_t ws_size,
                              hipStream_t stream) {
    if (n_in != 3) return;

    const float* data = (const float*)d_in[0];
    const unsigned int* dftw = (const unsigned int*)d_in[1];
    const float* leg  = (const float*)d_in[2];
    unsigned int* out = (unsigned int*)d_out;

    // ws: [legh][legl][At][fh]
    const size_t LEGN = (size_t)96 * 96 * 192;
    const size_t LEGB = 2 * LEGN * sizeof(unsigned short);   // 7.08 MB
    const size_t ATN  = (size_t)43008 * 192;                 // shorts
    const size_t ATB  = ATN * sizeof(unsigned short);        // 16.5 MB
    const size_t rowb = (size_t)192 * 192 * sizeof(unsigned short); // 73728 B / B-row
    if (ws_size < LEGB + ATB + 50 * rowb) return;

    unsigned short* legh = (unsigned short*)d_ws;
    unsigned short* legl = legh + LEGN;
    unsigned short* At   = legl + LEGN;

    size_t maxrows = (ws_size - LEGB - ATB) / rowb;
    int chunk = (int)((maxrows / 50) * 50);
    if (chunk > NB) chunk = NB;

    leg_conv_kernel<<<dim3((96 * 96 * 192 + 255) / 256), dim3(256), 0, stream>>>(
        leg, legh, legl);
    dft_transpose_kernel<<<dim3(192, 13), dim3(256), 0, stream>>>(dftw, At);

    for (int c0 = 0; c0 < NB; c0 += chunk) {
        int cn = NB - c0 < chunk ? NB - c0 : chunk;
        unsigned short* fh = At + ATN;

        int nbt = cn / 50;
        dim3 g1(96 * nbt);
        dft_mfma_kernel<<<g1, dim3(256), 0, stream>>>(data, At, fh, c0, cn);
        dim3 g2(96, nbt);
        leg_mfma_kernel<<<g2, dim3(256), 0, stream>>>(legh, legl, fh, out, c0, cn);
    }
}

// Round 15
// 93.348 us; speedup vs baseline: 1.0300x; 1.0068x over previous
//
#include <hip/hip_runtime.h>

#define NLAT 192
#define NPTS 40320
#define MMAX 96
#define LMAX 96
#define NV   100
#define MAXN 400
#define NB   400   // total B rows = 4 * NV

typedef __attribute__((ext_vector_type(8))) _Float16 half8v;  // 8 f16 (4 VGPRs)
typedef __attribute__((ext_vector_type(4))) float f32x4;

static __device__ __forceinline__ float bits2f(unsigned int b) {
    union { unsigned int i; float f; } v; v.i = b; return v.f;
}
static __device__ __forceinline__ unsigned int f2bf(float f) {
    union { float f; unsigned int i; } v; v.f = f;
    return (v.i + 0x7FFFu + ((v.i >> 16) & 1u)) >> 16;
}
static __device__ __forceinline__ unsigned short f2h(float f) {
    union { _Float16 h; unsigned short s; } u; u.h = (_Float16)f; return u.s;
}
static __device__ __forceinline__ float h2f(unsigned short s) {
    union { _Float16 h; unsigned short s; } u; u.s = s; return (float)u.h;
}
// split f32 pair -> hi f16 pair + lo f16 pair (residual), packed words
static __device__ __forceinline__ void split2(float a, float b,
                                              unsigned int& hw, unsigned int& lw) {
    unsigned short h0 = f2h(a), h1 = f2h(b);
    unsigned short l0 = f2h(a - h2f(h0)), l1 = f2h(b - h2f(h1));
    hw = (unsigned int)h0 | ((unsigned int)h1 << 16);
    lw = (unsigned int)l0 | ((unsigned int)l1 << 16);
}

// S(n) = sum_{t<n} floor(t/8)
static __device__ __forceinline__ int Ssum(int n) {
    int q = n >> 3, r = n & 7; return 4 * q * (q - 1) + q * r;
}
// padded-32 k-units before ring j in At (ragged layout); total = 43008
static __device__ __forceinline__ int atoffk(int j) {
    if (j < 96) return 32 * (Ssum(j + 12) - 4);
    return 32 * (672 + 676 - Ssum(204 - j));
}
static __device__ __forceinline__ int kpad_of(int j) {
    return 32 * ((j < 96 ? (j + 12) : (203 - j)) >> 3);
}

// ---------------- K0a: split leg fp32 -> f16 hi/lo, relayout [l][m][j] -> [m][l][j]
__global__ __launch_bounds__(256) void leg_conv_kernel(
    const float* __restrict__ leg,    // [96 l][96 m][192 j]
    unsigned short* __restrict__ legh,
    unsigned short* __restrict__ legl)
{
    int idx = blockIdx.x * 256 + threadIdx.x;
    if (idx >= 96 * 96 * 192) return;
    int j = idx % 192;
    int lm = idx / 192;
    int m = lm % 96, l = lm / 96;
    float v = leg[idx];
    unsigned short h = f2h(v);
    unsigned short lo = f2h(v - h2f(h));
    size_t o = ((size_t)m * 96 + l) * 192 + j;
    legh[o] = h;
    legl[o] = lo;
}

// ---------------- K0b: transpose dft words into At (f16), k-step-blocked:
// At[j]: per k-step t, contiguous [192 rows][32 k] f16 (12288 B)
__global__ __launch_bounds__(256) void dft_transpose_kernel(
    const unsigned int* __restrict__ dftw,   // [192][400][96] (bf16 re | im<<16)
    unsigned short* __restrict__ At)
{
    const int j = blockIdx.x;
    const int kpad = kpad_of(j);
    const int t = blockIdx.y;
    const int k0 = t * 32;
    if (k0 >= kpad) return;
    const int n = j < 96 ? 20 + 4 * j : 400 - 4 * (j - 96);
    unsigned short* abase = At + (size_t)atoffk(j) * 192 + (size_t)t * 6144;
    const int tid = threadIdx.x;
#pragma unroll
    for (int s = 0; s < 3; ++s) {
        int slot = s * 256 + tid;          // 768 = 192 rows x 4 chunks
        int row = slot % 192;
        int ch  = slot / 192;
        int m = row < 96 ? row : row - 96;
        bool isIm = row >= 96;
        const unsigned int* dp = dftw + ((size_t)j * MAXN + k0 + ch * 8) * 96 + m;
        unsigned short o[8];
#pragma unroll
        for (int i = 0; i < 8; ++i) {
            int k = k0 + ch * 8 + i;
            unsigned int v = (k < n) ? dp[(size_t)i * 96] : 0u;
            float f = isIm ? bits2f(v & 0xFFFF0000u) : bits2f(v << 16);
            o[i] = f2h(f);
        }
        uint4 pk;
        pk.x = (unsigned int)o[0] | ((unsigned int)o[1] << 16);
        pk.y = (unsigned int)o[2] | ((unsigned int)o[3] << 16);
        pk.z = (unsigned int)o[4] | ((unsigned int)o[5] << 16);
        pk.w = (unsigned int)o[6] | ((unsigned int)o[7] << 16);
        *(uint4*)(abase + (size_t)row * 32 + ch * 8) = pk;
    }
}

// ---------------- K1 (MFMA f16): ring DFT GEMM — no LDS/barriers, max TLP.
// Wave = (ring-pair pp, m-half mh, 16-col tile ct). Block = 4 waves =
// 2 pairs x 2 m-halves sharing ct. Grid = 48 pair-duos x 25 col-tiles = 1200
// blocks / 4800 balanced waves. X 2-deep reg prefetch; A at-use (L2, 25x reuse
// same-XCD: same-duo blocks differ by 48 = 0 mod 8).
__global__ __launch_bounds__(256, 4) void dft_mfma_kernel(
    const float* __restrict__ data,          // [4][NPTS][NV] fp32
    const unsigned short* __restrict__ At,   // ragged [j][t][192][32] f16
    unsigned short* __restrict__ fh)         // [NLAT][192][NB] f16
{
    const int id  = blockIdx.x;
    const int pg  = id % 48;                 // pair-duo (same-XCD At reuse)
    const int ct  = id / 48;                 // col tile 0..24
    const int tid = threadIdx.x;
    const int w   = tid >> 6;
    const int l   = tid & 63;
    const int lr  = l & 15;
    const int kg  = l >> 4;
    const int pp  = 2 * pg + (w >> 1);       // ring pair 0..95
    const int mh  = w & 1;                   // m-half: 0 = re rows, 1 = im rows

    const int Bb = ct * 16 + lr;             // global B col 0..399
    const int bb = Bb / NV, vv = Bb % NV;
    const float* dbase = data + (size_t)bb * NPTS * NV + vv;

    for (int rr = 0; rr < 2; ++rr) {
        int j, n, start;
        if (rr == 0) { j = pp;      n = 20 + 4 * pp;  start = 2 * pp * pp + 18 * pp; }
        else         { j = 96 + pp; n = 400 - 4 * pp; start = 20160 + 402 * pp - 2 * pp * pp; }
        const int nsteps = kpad_of(j) >> 5;
        const half8v* avb = (const half8v*)(At + (size_t)atoffk(j) * 192);

        f32x4 acc[6];
#pragma unroll
        for (int mt = 0; mt < 6; ++mt) acc[mt] = (f32x4){0.f, 0.f, 0.f, 0.f};

        float xfA[8], xfB[8];
        // prologue: X(0) -> A-buf, X(1) -> B-buf (addresses clamped; At rows
        // are zero beyond n so out-of-ring X values are multiplied by zero)
#pragma unroll
        for (int i = 0; i < 8; ++i) {
            int k = kg * 8 + i; if (k > n - 1) k = n - 1;
            xfA[i] = dbase[(size_t)(start + k) * NV];
        }
        if (nsteps > 1) {
#pragma unroll
            for (int i = 0; i < 8; ++i) {
                int k = 32 + kg * 8 + i; if (k > n - 1) k = n - 1;
                xfB[i] = dbase[(size_t)(start + k) * NV];
            }
        }

        for (int t = 0; t < nsteps; ++t) {
            float* xcur = (t & 1) ? xfB : xfA;
            // convert X(t)
            unsigned int BH[4], BL[4];
#pragma unroll
            for (int q = 0; q < 4; ++q)
                split2(xcur[2 * q], xcur[2 * q + 1], BH[q], BL[q]);
            // prefetch X(t+2) into the buffer just consumed
            if (t + 2 < nsteps) {
                int kb = (t + 2) * 32 + kg * 8;
#pragma unroll
                for (int i = 0; i < 8; ++i) {
                    int k = kb + i; if (k > n - 1) k = n - 1;
                    xcur[i] = dbase[(size_t)(start + k) * NV];
                }
            }
            // A at-use: 6 contiguous 16B frags for this m-half
            const half8v* av = avb + (size_t)t * 768;
            union { uint4 u; half8v h; } ubh, ubl;
            ubh.u = (uint4){BH[0], BH[1], BH[2], BH[3]};
            ubl.u = (uint4){BL[0], BL[1], BL[2], BL[3]};
#pragma unroll
            for (int mt = 0; mt < 6; ++mt) {
                half8v a = av[((mh * 96 + mt * 16) + lr) * 4 + kg];
                acc[mt] = __builtin_amdgcn_mfma_f32_16x16x32_f16(a, ubh.h, acc[mt], 0, 0, 0);
                acc[mt] = __builtin_amdgcn_mfma_f32_16x16x32_f16(a, ubl.h, acc[mt], 0, 0, 0);
            }
        }

        // epilogue: C/D col=lane&15 (B), row=(lane>>4)*4+reg; emit f16
#pragma unroll
        for (int mt = 0; mt < 6; ++mt) {
#pragma unroll
            for (int r = 0; r < 4; ++r)
                fh[((size_t)j * 192 + mh * 96 + mt * 16 + kg * 4 + r) * NB + Bb] =
                    f2h(acc[mt][r]);
        }
    }
}

// ---------------- K2 (MFMA f16): Legendre contraction — no LDS/barriers,
// F register double-buffered (the scattered-load latency tail).
static __device__ __forceinline__ void k2_step(
    unsigned short (&fcur)[2][8], unsigned short (&fnxt)[2][8],
    f32x4 (&acc)[6][2], int s, int m, int lr, int kg, int col,
    const unsigned short* __restrict__ legh,
    const unsigned short* __restrict__ legl,
    const unsigned short* __restrict__ fh)
{
    const int j0 = s * 32;
    half8v ah[6], al[6];
#pragma unroll
    for (int lt = 0; lt < 6; ++lt) {
        size_t o = ((size_t)m * 96 + lt * 16 + lr) * 192 + j0 + kg * 8;
        ah[lt] = *(const half8v*)&legh[o];
        al[lt] = *(const half8v*)&legl[o];
    }
    if (s + 1 < 6) {
        const int jn = (s + 1) * 32 + kg * 8;
#pragma unroll
        for (int pl = 0; pl < 2; ++pl)
#pragma unroll
            for (int i = 0; i < 8; ++i)
                fnxt[pl][i] = fh[((size_t)(jn + i) * 192 + m + 96 * pl) * NB + col];
    }
    half8v fF[2];
#pragma unroll
    for (int pl = 0; pl < 2; ++pl) {
        union { half8v h; unsigned short s16[8]; } uf;
#pragma unroll
        for (int i = 0; i < 8; ++i) uf.s16[i] = fcur[pl][i];
        fF[pl] = uf.h;
    }
#pragma unroll
    for (int lt = 0; lt < 6; ++lt)
#pragma unroll
        for (int pl = 0; pl < 2; ++pl) {
            acc[lt][pl] = __builtin_amdgcn_mfma_f32_16x16x32_f16(ah[lt], fF[pl], acc[lt][pl], 0, 0, 0);
            acc[lt][pl] = __builtin_amdgcn_mfma_f32_16x16x32_f16(al[lt], fF[pl], acc[lt][pl], 0, 0, 0);
        }
}

__global__ __launch_bounds__(256) void leg_mfma_kernel(
    const unsigned short* __restrict__ legh,  // [96 m][96 l][192 j] f16
    const unsigned short* __restrict__ legl,
    const unsigned short* __restrict__ fh,    // [192 j][192 mm][NB] f16
    unsigned int* __restrict__ out)           // [4][LMAX][MMAX][NV] packed bf16
{
    const int m   = blockIdx.x;
    const int bt  = blockIdx.y;
    const int tid = threadIdx.x;
    const int w   = tid >> 6;
    const int l   = tid & 63;
    const int lr  = l & 15;
    const int kg  = l >> 4;

    const int c  = w * 16 + lr;
    const bool cok = c < 50;
    const int col = bt * 50 + (cok ? c : 0);

    f32x4 acc[6][2];
#pragma unroll
    for (int lt = 0; lt < 6; ++lt)
#pragma unroll
        for (int pl = 0; pl < 2; ++pl) acc[lt][pl] = (f32x4){0.f, 0.f, 0.f, 0.f};

    unsigned short fA[2][8], fB[2][8];
#pragma unroll
    for (int pl = 0; pl < 2; ++pl)
#pragma unroll
        for (int i = 0; i < 8; ++i)
            fA[pl][i] = fh[((size_t)(kg * 8 + i) * 192 + m + 96 * pl) * NB + col];

#pragma unroll
    for (int ss = 0; ss < 3; ++ss) {
        k2_step(fA, fB, acc, 2 * ss,     m, lr, kg, col, legh, legl, fh);
        k2_step(fB, fA, acc, 2 * ss + 1, m, lr, kg, col, legh, legl, fh);
    }

    if (cok) {
        int B = bt * 50 + c;
        int bb = B / NV, vv = B % NV;
#pragma unroll
        for (int lt = 0; lt < 6; ++lt) {
#pragma unroll
            for (int r = 0; r < 4; ++r) {
                int ll = lt * 16 + kg * 4 + r;
                out[(((size_t)bb * LMAX + ll) * MMAX + m) * NV + vv] =
                    f2bf(acc[lt][0][r]) | (f2bf(acc[lt][1][r]) << 16);
            }
        }
    }
}

extern "C" void kernel_launch(void* const* d_in, const int* in_sizes, int n_in,
                              void* d_out, int out_size, void* d_ws, size_t ws_size,
                              hipStream_t stream) {
    if (n_in != 3) return;

    const float* data = (const float*)d_in[0];
    const unsigned int* dftw = (const unsigned int*)d_in[1];
    const float* leg  = (const float*)d_in[2];
    unsigned int* out = (unsigned int*)d_out;

    // ws: [legh][legl][At][fh]  (~53 MB total; harness ws has been >= 82 MB)
    const size_t LEGN = (size_t)96 * 96 * 192;
    const size_t LEGB = 2 * LEGN * sizeof(unsigned short);   // 7.08 MB
    const size_t ATN  = (size_t)43008 * 192;                 // shorts
    const size_t ATB  = ATN * sizeof(unsigned short);        // 16.5 MB
    const size_t FHB  = (size_t)192 * 192 * NB * sizeof(unsigned short); // 29.5 MB
    if (ws_size < LEGB + ATB + FHB) return;

    unsigned short* legh = (unsigned short*)d_ws;
    unsigned short* legl = legh + LEGN;
    unsigned short* At   = legl + LEGN;
    unsigned short* fh   = At + ATN;

    leg_conv_kernel<<<dim3((96 * 96 * 192 + 255) / 256), dim3(256), 0, stream>>>(
        leg, legh, legl);
    dft_transpose_kernel<<<dim3(192, 13), dim3(256), 0, stream>>>(dftw, At);

    dft_mfma_kernel<<<dim3(1200), dim3(256), 0, stream>>>(data, At, fh);
    leg_mfma_kernel<<<dim3(96, 8), dim3(256), 0, stream>>>(legh, legl, fh, out);
}